// Round 10
// baseline (864.349 us; speedup 1.0000x reference)
//
#include <hip/hip_runtime.h>
#include <math.h>

// ---------------------------------------------------------------------------
// SplineCNN forward. Edge message GEMMs in bf16 MFMA (fp32 accumulate),
// fp32 elsewhere. k0-bucketed edges (device count-sort, one per level).
// Round 10: node passes fused into gemm dispatches via "last contributor
// finishes" atomic counters. 17 dispatches.
// ---------------------------------------------------------------------------

static const int N1 = 10000, E1 = 60000;
static const int N2 = 2500,  E2 = 15000;
static const int N3 = 625,   E3 = 3750;
static const int N4 = 160,   E4 = 960;
static const int NC = 4;
static const int CHUNK = 64;

typedef __attribute__((ext_vector_type(8))) short bfrag;
typedef __attribute__((ext_vector_type(4))) float f32x4;

__device__ __forceinline__ float eluf(float x) { return x > 0.f ? x : expm1f(x); }

__device__ __forceinline__ unsigned short bfc(float f) {   // f32 -> bf16 RNE
    unsigned u = __float_as_uint(f);
    return (unsigned short)((u + 0x7FFF + ((u >> 16) & 1)) >> 16);
}

// ---------------------------------------------------------------------------
// init_misc: (A) W->bf16 packed conversion, (B) pool prefill, (C) agg zero,
// (D) hist/cursor/deg zero.
// ---------------------------------------------------------------------------
struct InitArgs {
    const float* wsrc[10]; unsigned short* wdst[10];
    int cinmat[10], xs_[10], cout[10];
    long welems[10];            // cumulative 8-GROUP end-offsets
    long wtot;
    float* pools[3]; int pM[3];
    float* agg; int aggN4;
    int* preblk; int preN;
    int bB, bC, bD;
};

__global__ __launch_bounds__(256) void init_misc(InitArgs A) {
    const int blk = blockIdx.x, tid = threadIdx.x;
    if (blk < A.bB) {                       // role A: weight conversion
        const long t = (long)blk * 256 + tid;
        if (t >= A.wtot) return;
        int k = 0;
        while (t >= A.welems[k]) ++k;
        const long i2 = t - (k ? A.welems[k - 1] : 0);
        const int co = A.cout[k], cm = A.cinmat[k], xs = A.xs_[k];
        const int KG = cm >> 3;
        const int o = (int)(i2 % co);
        const long rest = i2 / co;
        const int g8 = (int)(rest % KG);
        const int kk = (int)(rest / KG);
        const float* sp = A.wsrc[k] + ((size_t)kk * xs + g8 * 8) * co + o;
        bfrag bv;
        #pragma unroll
        for (int j = 0; j < 8; ++j) bv[j] = (short)bfc(sp[(size_t)j * co]);
        *(bfrag*)(A.wdst[k] + (((size_t)(kk * KG + g8)) * co + o) * 8) = bv;
    } else if (blk < A.bC) {                // role B: pool prefill
        const int t = (blk - A.bB) * 256 + tid;
        if (t >= A.pM[2]) return;
        const int p = (t < A.pM[0]) ? 0 : (t < A.pM[1] ? 1 : 2);
        const int base = p ? A.pM[p - 1] : 0;
        const int i2 = t - base;
        A.pools[p][i2] = (i2 % 65 == 64) ? 1.0f : -INFINITY;
    } else if (blk < A.bD) {                // role C: agg zero
        const int t = (blk - A.bC) * 256 + tid;
        if (t < A.aggN4) ((float4*)A.agg)[t] = make_float4(0.f, 0.f, 0.f, 0.f);
    } else {                                // role D: preblk zero
        const int t = (blk - A.bD) * 256 + tid;
        if (t < A.preN) A.preblk[t] = 0;
    }
}

// ---------------------------------------------------------------------------
// Batched preprocessing structs
// ---------------------------------------------------------------------------
struct Levels {
    const float* u[4]; const int* ei[4]; int E[4]; int Na[4];
    int nb0[5];   // cumulative 256-edge block offsets
    int cb0[5];   // cumulative fill_chunks block offsets
    int rb0[5];   // cumulative rem-init block offsets
    int mc[4];
    int* ek0[4]; int* hist[4]; int* cursor[4]; float* deg[4];
    int* ck0[4]; int* ccnt[4]; int* perm[4]; int* rem[4];
};

// Dispatch 2: prep (k0/hist/deg for all levels) + conv1 direct edge kernel.
__global__ __launch_bounds__(256) void prep_conv1(Levels L, const float* __restrict__ x,
                                                  const float* __restrict__ w1,
                                                  float* __restrict__ agg, int nbTot) {
    __shared__ int lh[64];
    const int tid = threadIdx.x;
    if ((int)blockIdx.x < nbTot) {
        int l = 0;
        while (l < 3 && (int)blockIdx.x >= L.nb0[l + 1]) ++l;
        const int bl = blockIdx.x - L.nb0[l];
        if (tid < 64) lh[tid] = 0;
        __syncthreads();
        const int e = bl * 256 + tid;
        if (e < L.E[l]) {
            int b = 0;
            #pragma unroll
            for (int d = 0; d < 3; ++d) {
                const float v = L.u[l][e * 3 + d] * 4.0f;
                const float kf = fminf(fmaxf(floorf(v), 0.f), 3.f);
                b = (b << 2) | (int)kf;
            }
            L.ek0[l][e] = b;
            atomicAdd(&lh[b], 1);
            atomicAdd(&L.deg[l][L.ei[l][L.E[l] + e]], 1.0f);
        }
        __syncthreads();
        if (tid < 64 && lh[tid]) atomicAdd(&L.hist[l][tid], lh[tid]);
    } else {
        // conv1: one wave per edge (64 lanes = 64 out channels)
        const int t = (blockIdx.x - nbTot) * 256 + tid;
        const int e = t >> 6, o = t & 63;
        if (e >= E1) return;
        const int src = L.ei[0][e], dst = L.ei[0][E1 + e];
        float f[3]; int kb = 0;
        #pragma unroll
        for (int d = 0; d < 3; ++d) {
            const float v = L.u[0][e * 3 + d] * 4.0f;
            const float kf = fminf(fmaxf(floorf(v), 0.f), 3.f);
            f[d] = v - kf; kb = kb * 5 + (int)kf;
        }
        float s = 0.f;
        #pragma unroll
        for (int c = 0; c < 8; ++c) {
            const int b0 = (c >> 2) & 1, b1 = (c >> 1) & 1, b2 = c & 1;
            const float wgt = (b0 ? f[0] : 1.f - f[0]) * (b1 ? f[1] : 1.f - f[1]) *
                              (b2 ? f[2] : 1.f - f[2]);
            s += wgt * w1[(size_t)(kb + b0 * 25 + b1 * 5 + b2) * 64 + o];
        }
        atomicAdd(&agg[(size_t)dst * 64 + o], x[src] * s);
    }
}

// Dispatch 3: fill_chunks + scatter (local prefix scan) + conv1 node + rem init.
__global__ __launch_bounds__(256) void fill_scatter_node1(
        Levels L, const float* __restrict__ x, float* __restrict__ agg,
        const float* __restrict__ r1, const float* __restrict__ b1,
        float* __restrict__ h1a, int cbTot, int nbTot, int n1B) {
    __shared__ int sb[65];
    __shared__ int lh[64], lbase[64];
    const int tid = threadIdx.x;
    const int blk = blockIdx.x;
    if (blk < cbTot) {
        int l = 0;
        while (l < 3 && blk >= L.cb0[l + 1]) ++l;
        if (tid == 0) {
            int cc = 0;
            for (int b = 0; b < 64; ++b) { sb[b] = cc; cc += (L.hist[l][b] + CHUNK - 1) / CHUNK; }
            sb[64] = cc;
        }
        __syncthreads();
        const int c = (blk - L.cb0[l]) * 256 + tid;
        if (c < L.mc[l]) {
            if (c >= sb[64]) { L.ccnt[l][c] = 0; L.ck0[l][c] = 0; }
            else {
                int lo = 0, hi = 64;
                while (hi - lo > 1) { int m = (lo + hi) >> 1; if (sb[m] <= c) lo = m; else hi = m; }
                const int j = c - sb[lo];
                L.ck0[l][c] = lo;
                L.ccnt[l][c] = min(CHUNK, L.hist[l][lo] - j * CHUNK);
            }
        }
    } else if (blk < cbTot + nbTot) {
        const int fb = blk - cbTot;
        int l = 0;
        while (l < 3 && fb >= L.nb0[l + 1]) ++l;
        const int bl = fb - L.nb0[l];
        if (tid == 0) {
            int cc = 0;
            for (int b = 0; b < 64; ++b) { sb[b] = cc; cc += (L.hist[l][b] + CHUNK - 1) / CHUNK; }
        }
        if (tid < 64) lh[tid] = 0;
        __syncthreads();
        const int e = bl * 256 + tid;
        int b = -1, r = 0;
        if (e < L.E[l]) { b = L.ek0[l][e]; r = atomicAdd(&lh[b], 1); }
        __syncthreads();
        if (tid < 64) lbase[tid] = lh[tid] ? atomicAdd(&L.cursor[l][tid], lh[tid]) : 0;
        __syncthreads();
        if (e < L.E[l]) L.perm[l][sb[b] * CHUNK + lbase[b] + r] = e;
    } else if (blk < cbTot + nbTot + n1B) {
        // conv1 node pass
        const int nb = blk - cbTot - nbTot;
        const int lane = tid & 63;
        const int grp  = tid >> 6;
        const int n = nb * 4 + grp;
        if (n >= N1) return;
        const float d = fmaxf(L.deg[0][n], 1.f);
        const size_t idx = (size_t)n * 64 + lane;
        float s = agg[idx] / d + b1[lane];
        agg[idx] = 0.f;
        s += x[n] * r1[lane];
        h1a[idx] = eluf(s);
    } else {
        // rem init: rem[l][n] = deg[l][n] + 1 (the +1 is the virtual decrement)
        const int rb = blk - cbTot - nbTot - n1B;
        int l = 0;
        while (l < 3 && rb >= L.rb0[l + 1]) ++l;
        const int n = (rb - L.rb0[l]) * 256 + tid;
        if (n < L.Na[l]) L.rem[l][n] = (int)L.deg[l][n] + 1;
    }
}

// ---------------------------------------------------------------------------
// Node finisher (wave-cooperative, 64 lanes). Same math as the old node kernel.
// ---------------------------------------------------------------------------
enum { M_PLAIN = 0, M_SEGMAX = 1, M_FC1 = 2, M_LSM = 3 };

template<int COUT, int XS, int MODE>
__device__ __forceinline__ void finish_node(
        int n, const float* __restrict__ x, float* __restrict__ agg,
        const float* __restrict__ deg, const float* __restrict__ R,
        const float* __restrict__ bb, float* __restrict__ outp,
        const int* __restrict__ cl, float* __restrict__ pool,
        const float* __restrict__ fw, const float* __restrict__ fb2,
        float* __restrict__ fout, int* __restrict__ rem) {
    const int lane = threadIdx.x & 63;
    const float dr = deg[n];
    const float d = fmaxf(dr, 1.f);
    float val = 0.f;
    if (COUT == 64 || lane < 32) {
        const size_t idx = (size_t)n * COUT + lane;
        // L1-bypassing load/store: agg was written by L2 atomics from other CUs
        float s = __hip_atomic_load(&agg[idx], __ATOMIC_RELAXED, __HIP_MEMORY_SCOPE_AGENT) / d
                  + bb[lane];
        __hip_atomic_store(&agg[idx], 0.f, __ATOMIC_RELAXED, __HIP_MEMORY_SCOPE_AGENT);
        const float* xs = x + (size_t)n * XS;
        #pragma unroll 4
        for (int i = 0; i < XS; ++i) s += xs[i] * R[i * COUT + lane];
        val = eluf(s);
        if (MODE == M_PLAIN || MODE == M_SEGMAX) outp[idx] = val;
        if (MODE == M_SEGMAX) {
            float* addr = pool + (size_t)cl[n] * 65 + lane;
            if (val >= 0.f) atomicMax((int*)addr, __float_as_int(val));
            else            atomicMin((unsigned int*)addr, __float_as_uint(val));
        }
        if (MODE == M_LSM) {
            float p[NC];
            #pragma unroll
            for (int o = 0; o < NC; ++o) p[o] = val * fw[lane * NC + o];
            #pragma unroll
            for (int m = 16; m >= 1; m >>= 1)
                #pragma unroll
                for (int o = 0; o < NC; ++o) p[o] += __shfl_xor(p[o], m, 32);
            #pragma unroll
            for (int o = 0; o < NC; ++o) p[o] += fb2[o];
            const float mx = fmaxf(fmaxf(p[0], p[1]), fmaxf(p[2], p[3]));
            float se = 0.f;
            #pragma unroll
            for (int o = 0; o < NC; ++o) se += expf(p[o] - mx);
            const float lg = logf(se);
            if (lane < NC) fout[(size_t)n * NC + lane] = p[lane] - mx - lg;
        }
    }
    if (MODE == M_FC1) {                 // COUT==64: fc1 64->32 via shfl
        float s2 = fb2[lane & 31];
        #pragma unroll 4
        for (int i = 0; i < 64; ++i) s2 += __shfl(val, i, 64) * fw[i * 32 + (lane & 31)];
        if (lane < 32) fout[(size_t)n * 32 + lane] = eluf(s2);
    }
    if (lane == 0)                       // re-arm for this level's next conv
        __hip_atomic_store(&rem[n], (int)dr + 1, __ATOMIC_RELAXED, __HIP_MEMORY_SCOPE_AGENT);
}

// ---------------------------------------------------------------------------
// MFMA bucket-GEMM + inline node finish. Grid = mc chunk blocks + ceil(N/256)
// virtual-decrement blocks (cover deg-0 nodes).
// ---------------------------------------------------------------------------
template<int CINMAT, int COUT, bool HAS_ONES, int MODE>
__global__ __launch_bounds__(256) void bucket_gemm_f(
        const float* __restrict__ x, const int* __restrict__ ei, const float* __restrict__ u,
        const unsigned short* __restrict__ Wt, const float* __restrict__ Wf,
        const int* __restrict__ perm, const int* __restrict__ ck0, const int* __restrict__ ccnt,
        float* __restrict__ agg, int E, int mc, int N,
        int* __restrict__ rem, const float* __restrict__ deg,
        const float* __restrict__ R, const float* __restrict__ bb, float* __restrict__ outp,
        const int* __restrict__ cl, float* __restrict__ pool,
        const float* __restrict__ fw, const float* __restrict__ fb2, float* __restrict__ fout) {
    constexpr int ALDA = CINMAT + 8;
    constexpr int KG   = CINMAT / 8;
    constexpr int NT   = COUT / 16;
    constexpr int HALVES = CINMAT / 32;
    constexpr int XS   = CINMAT + (HAS_ONES ? 1 : 0);
    constexpr int IT   = CINMAT / 4;

    const int blk = blockIdx.x;
    const int tid = threadIdx.x;

    if (blk >= mc) {                     // virtual-decrement block
        const int wid = tid >> 6, lane = tid & 63;
        const int base = (blk - mc) * 256 + wid * 64;
        const int n = base + lane;
        bool win = false;
        if (n < N) win = (atomicSub(&rem[n], 1) == 1);
        unsigned long long wm = __ballot(win);
        while (wm) {
            const int i = __ffsll(wm) - 1;
            wm &= wm - 1;
            finish_node<COUT, XS, MODE>(base + i, x, agg, deg, R, bb, outp,
                                        cl, pool, fw, fb2, fout, rem);
        }
        return;
    }

    __shared__ unsigned short A0s[64 * ALDA], A1s[64 * ALDA];
    __shared__ float gS[64 * 4], sS[64 * 2];
    __shared__ int srcS[64], dstS[64];
    __shared__ float WonesS[HAS_ONES ? 8 * COUT : 4];

    const int cnt = ccnt[blk];
    if (cnt == 0) return;
    const int b = ck0[blk];
    const int kbase = ((b >> 4) & 3) * 25 + ((b >> 2) & 3) * 5 + (b & 3);
    const int cstart = blk * CHUNK;

    if (tid < CHUNK) {
        const int e = tid;
        const int pe = (e < cnt) ? perm[cstart + e] : -1;
        int sv = -1, dv = 0;
        float g0 = 0, g1 = 0, g2 = 0, g3 = 0, s0 = 0, s1 = 0;
        if (pe >= 0) {
            sv = ei[pe]; dv = ei[E + pe];
            float f[3];
            #pragma unroll
            for (int d2 = 0; d2 < 3; ++d2) {
                const float v = u[pe * 3 + d2] * 4.f;
                const float kf = fminf(fmaxf(floorf(v), 0.f), 3.f);
                f[d2] = v - kf;
            }
            g0 = (1.f - f[0]) * (1.f - f[1]); g1 = (1.f - f[0]) * f[1];
            g2 = f[0] * (1.f - f[1]);         g3 = f[0] * f[1];
            s0 = 1.f - f[2]; s1 = f[2];
        }
        srcS[e] = sv; dstS[e] = dv;
        gS[e * 4 + 0] = g0; gS[e * 4 + 1] = g1; gS[e * 4 + 2] = g2; gS[e * 4 + 3] = g3;
        sS[e * 2 + 0] = s0; sS[e * 2 + 1] = s1;
    }
    if (HAS_ONES) {
        for (int t2 = tid; t2 < 8 * COUT; t2 += 256) {
            const int c = t2 / COUT, o = t2 % COUT;
            const int koff = ((c >> 2) & 1) * 25 + ((c >> 1) & 1) * 5 + (c & 1);
            WonesS[t2] = Wf[((size_t)(kbase + koff) * XS + CINMAT) * COUT + o];
        }
    }
    __syncthreads();

    {   // stage A0/A1 (bf16), 4 threads per edge
        const int e  = tid >> 2;
        const int ib = (tid & 3) * IT;
        const int sv = srcS[e];
        const float sc0 = sS[e * 2], sc1 = sS[e * 2 + 1];
        float xv[IT];
        if ((XS & 3) == 0) {
            #pragma unroll
            for (int j = 0; j < IT; j += 4) {
                float4 q = make_float4(0.f, 0.f, 0.f, 0.f);
                if (sv >= 0) q = *(const float4*)&x[(size_t)sv * XS + ib + j];
                xv[j] = q.x; xv[j + 1] = q.y; xv[j + 2] = q.z; xv[j + 3] = q.w;
            }
        } else {
            #pragma unroll
            for (int j = 0; j < IT; ++j) xv[j] = (sv >= 0) ? x[(size_t)sv * XS + ib + j] : 0.f;
        }
        #pragma unroll
        for (int j = 0; j < IT; j += 2) {
            const unsigned p0 = bfc(xv[j] * sc0) | ((unsigned)bfc(xv[j + 1] * sc0) << 16);
            const unsigned p1 = bfc(xv[j] * sc1) | ((unsigned)bfc(xv[j + 1] * sc1) << 16);
            *(unsigned*)&A0s[e * ALDA + ib + j] = p0;
            *(unsigned*)&A1s[e * ALDA + ib + j] = p1;
        }
    }
    __syncthreads();

    const int lane = tid & 63;
    const int wid  = tid >> 6;
    const int m0   = wid * 16;
    const int arow = m0 + (lane & 15);
    const int kg   = lane >> 4;
    const int ocol = lane & 15;

    f32x4 acc[4][NT];
    #pragma unroll
    for (int q = 0; q < 4; ++q)
        #pragma unroll
        for (int nt = 0; nt < NT; ++nt) acc[q][nt] = (f32x4){0.f, 0.f, 0.f, 0.f};

    #pragma unroll
    for (int q = 0; q < 4; ++q) {
        #pragma unroll
        for (int b2 = 0; b2 < 2; ++b2) {
            const unsigned short* Ab = b2 ? A1s : A0s;
            const int koff = (q >> 1) * 25 + (q & 1) * 5 + b2;
            #pragma unroll
            for (int hf = 0; hf < HALVES; ++hf) {
                const bfrag a = *(const bfrag*)(Ab + arow * ALDA + hf * 32 + kg * 8);
                const int krow = (kbase + koff) * KG + hf * 4 + kg;
                #pragma unroll
                for (int nt = 0; nt < NT; ++nt) {
                    const bfrag bbv = *(const bfrag*)(Wt + ((size_t)krow * COUT + nt * 16 + ocol) * 8);
                    acc[q][nt] = __builtin_amdgcn_mfma_f32_16x16x32_bf16(a, bbv, acc[q][nt], 0, 0, 0);
                }
            }
        }
    }

    const int grp = lane >> 4;
    #pragma unroll
    for (int nt = 0; nt < NT; ++nt) {
        const int o = nt * 16 + ocol;
        float wo[8];
        if (HAS_ONES) {
            #pragma unroll
            for (int c = 0; c < 8; ++c) wo[c] = WonesS[c * COUT + o];
        }
        #pragma unroll
        for (int r = 0; r < 4; ++r) {
            const int e = m0 + grp * 4 + r;
            if (e < cnt) {
                const float g0 = gS[e * 4 + 0], g1 = gS[e * 4 + 1];
                const float g2 = gS[e * 4 + 2], g3 = gS[e * 4 + 3];
                float v = g0 * acc[0][nt][r] + g1 * acc[1][nt][r] +
                          g2 * acc[2][nt][r] + g3 * acc[3][nt][r];
                if (HAS_ONES) {
                    const float s0v = sS[e * 2], s1v = sS[e * 2 + 1];
                    v += g0 * (s0v * wo[0] + s1v * wo[1]) + g1 * (s0v * wo[2] + s1v * wo[3]) +
                         g2 * (s0v * wo[4] + s1v * wo[5]) + g3 * (s0v * wo[6] + s1v * wo[7]);
                }
                atomicAdd(&agg[(size_t)dstS[e] * COUT + o], v);
            }
        }
    }

    // ---- inline node finish: last contributor per dst wins ----
    __syncthreads();                 // drains this block's agg atomics (vmcnt 0)
    __threadfence();                 // device-scope release
    const int e4 = wid * 16 + lane;  // wave w owns edges [16w, 16w+16)
    bool win = false;
    if (lane < 16 && e4 < cnt) win = (atomicSub(&rem[dstS[e4]], 1) == 1);
    unsigned long long wm = __ballot(win);
    while (wm) {
        const int i = __ffsll(wm) - 1;
        wm &= wm - 1;
        finish_node<COUT, XS, MODE>(dstS[wid * 16 + i], x, agg, deg, R, bb, outp,
                                    cl, pool, fw, fb2, fout, rem);
    }
}

__global__ void skip_gather(const float* __restrict__ up, const int* __restrict__ cl,
                            const float* __restrict__ h, const float* __restrict__ skw,
                            const float* __restrict__ skb, float* __restrict__ out, int N) {
    const int lane = threadIdx.x & 31;
    const int grp  = threadIdx.x >> 5;
    const int n = blockIdx.x * 8 + grp;
    if (n >= N) return;
    float s = up[(size_t)cl[n] * 32 + lane] + skb[lane];
    const float* hs = h + (size_t)n * 64;
    #pragma unroll 4
    for (int i = 0; i < 64; ++i) s += hs[i] * skw[i * 32 + lane];
    out[(size_t)n * 32 + lane] = s;
}

// ---------------------------------------------------------------------------
// Host orchestration
// ---------------------------------------------------------------------------
struct HLevel {
    const int* ei; const float* u; int E; int maxchunks; int N; int vb;
    int *ek0, *hist, *cursor, *ck0, *ccnt, *perm, *rem;
    float* deg;
};

extern "C" void kernel_launch(void* const* d_in, const int* in_sizes, int n_in,
                              void* d_out, int out_size, void* d_ws, size_t ws_size,
                              hipStream_t stream) {
    const float* x    = (const float*)d_in[0];
    const int*   ei1  = (const int*)  d_in[1];
    const float* u1   = (const float*)d_in[2];
    const int*   ei2  = (const int*)  d_in[3];
    const float* u2   = (const float*)d_in[4];
    const int*   ei3  = (const int*)  d_in[5];
    const float* u3   = (const float*)d_in[6];
    const int*   ei4  = (const int*)  d_in[7];
    const float* u4   = (const float*)d_in[8];
    const int*   c1   = (const int*)  d_in[9];
    const int*   c2   = (const int*)  d_in[10];
    const int*   c3   = (const int*)  d_in[11];
    const float *w1  = (const float*)d_in[12], *r1  = (const float*)d_in[13], *b1  = (const float*)d_in[14];
    const float *w12 = (const float*)d_in[15], *r12 = (const float*)d_in[16], *b12 = (const float*)d_in[17];
    const float *w2  = (const float*)d_in[18], *r2  = (const float*)d_in[19], *b2  = (const float*)d_in[20];
    const float *w22 = (const float*)d_in[21], *r22 = (const float*)d_in[22], *b22 = (const float*)d_in[23];
    const float *w3  = (const float*)d_in[24], *r3  = (const float*)d_in[25], *b3  = (const float*)d_in[26];
    const float *w32 = (const float*)d_in[27], *r32 = (const float*)d_in[28], *b32 = (const float*)d_in[29];
    const float *w4  = (const float*)d_in[30], *r4  = (const float*)d_in[31], *b4  = (const float*)d_in[32];
    const float *w42 = (const float*)d_in[33], *r42 = (const float*)d_in[34], *b42 = (const float*)d_in[35];
    const float *w5  = (const float*)d_in[36], *r5  = (const float*)d_in[37], *b5  = (const float*)d_in[38];
    const float *w6  = (const float*)d_in[39], *r6  = (const float*)d_in[40], *b6  = (const float*)d_in[41];
    const float *w7  = (const float*)d_in[42], *r7  = (const float*)d_in[43], *b7  = (const float*)d_in[44];
    const float *fc1w = (const float*)d_in[45], *fc1b = (const float*)d_in[46];
    const float *fc2w = (const float*)d_in[47], *fc2b = (const float*)d_in[48];
    const float *sk1w = (const float*)d_in[49], *sk1b = (const float*)d_in[50];
    const float *sk2w = (const float*)d_in[51], *sk2b = (const float*)d_in[52];
    const float *sk3w = (const float*)d_in[53], *sk3b = (const float*)d_in[54];
    float* out = (float*)d_out;

    char* wsb = (char*)d_ws;
    size_t off = 0;
    auto alloc = [&](size_t bytes) {
        void* p = wsb + off; off = (off + bytes + 255) & ~(size_t)255; return p;
    };
    auto allocF = [&](size_t n) { return (float*)alloc(n * 4); };
    auto allocI = [&](size_t n) { return (int*)alloc(n * 4); };
    auto allocH = [&](size_t n) { return (unsigned short*)alloc(n * 2); };

    float* h1a  = allocF((size_t)N1 * 64);
    float* h1   = allocF((size_t)N1 * 64);
    float* h2in = allocF((size_t)N2 * 65);
    float* h2a  = allocF((size_t)N2 * 64);
    float* h2   = allocF((size_t)N2 * 64);
    float* h3in = allocF((size_t)N3 * 65);
    float* h3a  = allocF((size_t)N3 * 64);
    float* h3   = allocF((size_t)N3 * 64);
    float* h4in = allocF((size_t)N4 * 65);
    float* h4a  = allocF((size_t)N4 * 64);
    float* h4b  = allocF((size_t)N4 * 64);
    float* h4   = allocF((size_t)N4 * 32);
    float* g3in = allocF((size_t)N3 * 32);
    float* g3   = allocF((size_t)N3 * 32);
    float* g2in = allocF((size_t)N2 * 32);
    float* g2   = allocF((size_t)N2 * 32);
    float* g1in = allocF((size_t)N1 * 32);
    float* agg  = allocF((size_t)N1 * 64);

    const size_t SZ64 = (size_t)125 * 8 * 64 * 8;
    const size_t SZ32 = (size_t)125 * 4 * 32 * 8;
    unsigned short* t12 = allocH(SZ64);
    unsigned short* t22 = allocH(SZ64);
    unsigned short* t32 = allocH(SZ64);
    unsigned short* t42 = allocH(SZ64);
    unsigned short* t2  = allocH(SZ64);
    unsigned short* t3  = allocH(SZ64);
    unsigned short* t4  = allocH(SZ64);
    unsigned short* t5  = allocH(SZ32);
    unsigned short* t6  = allocH(SZ32);
    unsigned short* t7  = allocH(SZ32);

    HLevel L[4];
    const int*   eis[4] = {ei1, ei2, ei3, ei4};
    const float* us [4] = {u1, u2, u3, u4};
    const int    Es [4] = {E1, E2, E3, E4};
    const int    Ns [4] = {N1, N2, N3, N4};

    int preN = 0;
    for (int l = 0; l < 4; ++l) preN += 128 + Ns[l];
    int* preblk = allocI(preN);
    {
        int c = 0;
        for (int l = 0; l < 4; ++l) {
            L[l].ei = eis[l]; L[l].u = us[l]; L[l].E = Es[l]; L[l].N = Ns[l];
            L[l].maxchunks = (Es[l] + CHUNK - 1) / CHUNK + 64;
            L[l].vb = (Ns[l] + 255) / 256;
            L[l].hist = preblk + c; L[l].cursor = preblk + c + 64;
            L[l].deg = (float*)(preblk + c + 128);
            c += 128 + Ns[l];
            L[l].ek0     = allocI(Es[l]);
            L[l].ck0     = allocI(L[l].maxchunks);
            L[l].ccnt    = allocI(L[l].maxchunks);
            L[l].perm    = allocI((size_t)L[l].maxchunks * CHUNK);
            L[l].rem     = allocI(Ns[l]);
        }
    }

    // ---- dispatch 1: init_misc ----
    InitArgs IA;
    {
        const float* srcs[10] = {w12, w22, w32, w42, w2, w3, w4, w5, w6, w7};
        unsigned short* dsts[10] = {t12, t22, t32, t42, t2, t3, t4, t5, t6, t7};
        const int cms[10] = {64,64,64,64,64,64,64,32,32,32};
        const int xss[10] = {64,64,64,64,65,65,65,32,32,32};
        const int cos[10] = {64,64,64,64,64,64,64,32,32,32};
        long cum = 0;
        for (int k = 0; k < 10; ++k) {
            IA.wsrc[k] = srcs[k]; IA.wdst[k] = dsts[k];
            IA.cinmat[k] = cms[k]; IA.xs_[k] = xss[k]; IA.cout[k] = cos[k];
            cum += (long)125 * (cms[k] / 8) * cos[k];
            IA.welems[k] = cum;
        }
        IA.wtot = cum;
        IA.pools[0] = h2in; IA.pools[1] = h3in; IA.pools[2] = h4in;
        IA.pM[0] = N2 * 65; IA.pM[1] = N2 * 65 + N3 * 65; IA.pM[2] = N2 * 65 + N3 * 65 + N4 * 65;
        IA.agg = agg; IA.aggN4 = N1 * 64 / 4;
        IA.preblk = preblk; IA.preN = preN;
        const int bA = (int)((IA.wtot + 255) / 256);
        const int bB = (IA.pM[2] + 255) / 256;
        const int bC = (IA.aggN4 + 255) / 256;
        const int bD = (preN + 255) / 256;
        IA.bB = bA; IA.bC = bA + bB; IA.bD = bA + bB + bC;
        init_misc<<<bA + bB + bC + bD, 256, 0, stream>>>(IA);
    }

    // ---- dispatches 2-3: preprocessing + conv1 + rem init ----
    Levels DL;
    int nbTot = 0, cbTot = 0, rbTot = 0;
    {
        for (int l = 0; l < 4; ++l) {
            DL.u[l] = L[l].u; DL.ei[l] = L[l].ei; DL.E[l] = L[l].E; DL.Na[l] = L[l].N;
            DL.nb0[l] = nbTot; nbTot += (L[l].E + 255) / 256;
            DL.cb0[l] = cbTot; cbTot += (L[l].maxchunks + 255) / 256;
            DL.rb0[l] = rbTot; rbTot += L[l].vb;
            DL.mc[l] = L[l].maxchunks;
            DL.ek0[l] = L[l].ek0; DL.hist[l] = L[l].hist; DL.cursor[l] = L[l].cursor;
            DL.deg[l] = L[l].deg;
            DL.ck0[l] = L[l].ck0; DL.ccnt[l] = L[l].ccnt; DL.perm[l] = L[l].perm;
            DL.rem[l] = L[l].rem;
        }
        DL.nb0[4] = nbTot; DL.cb0[4] = cbTot; DL.rb0[4] = rbTot;
        const int conv1B = (E1 * 64) / 256;
        prep_conv1<<<nbTot + conv1B, 256, 0, stream>>>(DL, x, w1, agg, nbTot);
        const int n1B = (N1 + 3) / 4;
        fill_scatter_node1<<<cbTot + nbTot + n1B + rbTot, 256, 0, stream>>>(
            DL, x, agg, r1, b1, h1a, cbTot, nbTot, n1B);
    }

    // ---- fused conv dispatches (gemm + inline node finish) ----
    #define GEMMF(CM, CO, HO, MODE, XIN, WT, WF, LV, RR, BB, OUTP, CL, POOL, FW, FB, FOUT) \
        bucket_gemm_f<CM, CO, HO, MODE><<<L[LV].maxchunks + L[LV].vb, 256, 0, stream>>>(   \
            XIN, L[LV].ei, L[LV].u, WT, WF, L[LV].perm, L[LV].ck0, L[LV].ccnt, agg,        \
            L[LV].E, L[LV].maxchunks, L[LV].N, L[LV].rem, L[LV].deg,                       \
            RR, BB, OUTP, CL, POOL, FW, FB, FOUT)

    // Level 1
    GEMMF(64, 64, false, M_SEGMAX, h1a, t12, nullptr, 0, r12, b12, h1, c1, h2in,
          nullptr, nullptr, nullptr);
    // Level 2
    GEMMF(64, 64, true,  M_PLAIN,  h2in, t2, w2, 1, r2, b2, h2a, nullptr, nullptr,
          nullptr, nullptr, nullptr);
    GEMMF(64, 64, false, M_SEGMAX, h2a, t22, nullptr, 1, r22, b22, h2, c2, h3in,
          nullptr, nullptr, nullptr);
    // Level 3
    GEMMF(64, 64, true,  M_PLAIN,  h3in, t3, w3, 2, r3, b3, h3a, nullptr, nullptr,
          nullptr, nullptr, nullptr);
    GEMMF(64, 64, false, M_SEGMAX, h3a, t32, nullptr, 2, r32, b32, h3, c3, h4in,
          nullptr, nullptr, nullptr);
    // Level 4
    GEMMF(64, 64, true,  M_PLAIN,  h4in, t4, w4, 3, r4, b4, h4a, nullptr, nullptr,
          nullptr, nullptr, nullptr);
    GEMMF(64, 64, false, M_PLAIN,  h4a, t42, nullptr, 3, r42, b42, h4b, nullptr, nullptr,
          nullptr, nullptr, nullptr);
    GEMMF(64, 64, false, M_FC1,    h4b, t42, nullptr, 3, r42, b42, nullptr, nullptr, nullptr,
          fc1w, fc1b, h4);

    // Decoder
    skip_gather<<<(N3 + 7) / 8, 256, 0, stream>>>(h4, c3, h3, sk3w, sk3b, g3in, N3);
    GEMMF(32, 32, false, M_PLAIN,  g3in, t5, nullptr, 2, r5, b5, g3, nullptr, nullptr,
          nullptr, nullptr, nullptr);
    skip_gather<<<(N2 + 7) / 8, 256, 0, stream>>>(g3, c2, h2, sk2w, sk2b, g2in, N2);
    GEMMF(32, 32, false, M_PLAIN,  g2in, t6, nullptr, 1, r6, b6, g2, nullptr, nullptr,
          nullptr, nullptr, nullptr);
    skip_gather<<<(N1 + 7) / 8, 256, 0, stream>>>(g2, c1, h1, sk1w, sk1b, g1in, N1);
    GEMMF(32, 32, false, M_LSM,    g1in, t7, nullptr, 0, r7, b7, nullptr, nullptr, nullptr,
          fc2w, fc2b, out);
    #undef GEMMF
}

// Round 11
// 269.858 us; speedup vs baseline: 3.2030x; 3.2030x over previous
//
#include <hip/hip_runtime.h>
#include <math.h>

// ---------------------------------------------------------------------------
// SplineCNN forward. Edge message GEMMs in bf16 MFMA (fp32 accumulate),
// everything else fp32. k0-bucketed edges (device count-sort, one per level).
// Round 11: round-7 structure (best known, 284us) + scan folded into
// fill/scatter (verified safe in round 8). 28 dispatches.
// Excluded by experiment: grid barriers (45us each), single-WG fusion
// (latency-bound), last-contributor fusion (fence+serialization), skip-fold
// into L0 gemm staging (redundant per-edge work).
// ---------------------------------------------------------------------------

static const int N1 = 10000, E1 = 60000;
static const int N2 = 2500,  E2 = 15000;
static const int N3 = 625,   E3 = 3750;
static const int N4 = 160,   E4 = 960;
static const int NC = 4;
static const int CHUNK = 64;

typedef __attribute__((ext_vector_type(8))) short bfrag;
typedef __attribute__((ext_vector_type(4))) float f32x4;

__device__ __forceinline__ float eluf(float x) { return x > 0.f ? x : expm1f(x); }

__device__ __forceinline__ unsigned short bfc(float f) {   // f32 -> bf16 RNE
    unsigned u = __float_as_uint(f);
    return (unsigned short)((u + 0x7FFF + ((u >> 16) & 1)) >> 16);
}

// ---------------------------------------------------------------------------
// init_misc: (A) W->bf16 packed conversion (1 thread per 8-elem k-group, 16B
// coalesced store), (B) pool prefill, (C) agg zero, (D) hist/cursor/deg zero.
// ---------------------------------------------------------------------------
struct InitArgs {
    const float* wsrc[10]; unsigned short* wdst[10];
    int cinmat[10], xs_[10], cout[10];
    long welems[10];            // cumulative 8-GROUP end-offsets
    long wtot;
    float* pools[3]; int pM[3];
    float* agg; int aggN4;
    int* preblk; int preN;
    int bB, bC, bD;
};

__global__ __launch_bounds__(256) void init_misc(InitArgs A) {
    const int blk = blockIdx.x, tid = threadIdx.x;
    if (blk < A.bB) {                       // role A: weight conversion
        const long t = (long)blk * 256 + tid;
        if (t >= A.wtot) return;
        int k = 0;
        while (t >= A.welems[k]) ++k;
        const long i2 = t - (k ? A.welems[k - 1] : 0);
        const int co = A.cout[k], cm = A.cinmat[k], xs = A.xs_[k];
        const int KG = cm >> 3;
        const int o = (int)(i2 % co);
        const long rest = i2 / co;
        const int g8 = (int)(rest % KG);
        const int kk = (int)(rest / KG);
        const float* sp = A.wsrc[k] + ((size_t)kk * xs + g8 * 8) * co + o;
        bfrag bv;
        #pragma unroll
        for (int j = 0; j < 8; ++j) bv[j] = (short)bfc(sp[(size_t)j * co]);
        *(bfrag*)(A.wdst[k] + (((size_t)(kk * KG + g8)) * co + o) * 8) = bv;
    } else if (blk < A.bC) {                // role B: pool prefill
        const int t = (blk - A.bB) * 256 + tid;
        if (t >= A.pM[2]) return;
        const int p = (t < A.pM[0]) ? 0 : (t < A.pM[1] ? 1 : 2);
        const int base = p ? A.pM[p - 1] : 0;
        const int i2 = t - base;
        A.pools[p][i2] = (i2 % 65 == 64) ? 1.0f : -INFINITY;
    } else if (blk < A.bD) {                // role C: agg zero
        const int t = (blk - A.bC) * 256 + tid;
        if (t < A.aggN4) ((float4*)A.agg)[t] = make_float4(0.f, 0.f, 0.f, 0.f);
    } else {                                // role D: preblk zero
        const int t = (blk - A.bD) * 256 + tid;
        if (t < A.preN) A.preblk[t] = 0;
    }
}

// ---------------------------------------------------------------------------
// Batched preprocessing structs
// ---------------------------------------------------------------------------
struct Levels {
    const float* u[4]; const int* ei[4]; int E[4];
    int nb0[5];   // cumulative 256-edge block offsets
    int cb0[5];   // cumulative fill_chunks block offsets
    int mc[4];
    int* ek0[4]; int* hist[4]; int* cursor[4]; float* deg[4];
    int* ck0[4]; int* ccnt[4]; int* perm[4];
};

// Dispatch 2: prep (k0/hist/deg for all levels) + conv1 direct edge kernel.
__global__ __launch_bounds__(256) void prep_conv1(Levels L, const float* __restrict__ x,
                                                  const float* __restrict__ w1,
                                                  float* __restrict__ agg, int nbTot) {
    __shared__ int lh[64];
    const int tid = threadIdx.x;
    if ((int)blockIdx.x < nbTot) {
        int l = 0;
        while (l < 3 && (int)blockIdx.x >= L.nb0[l + 1]) ++l;
        const int bl = blockIdx.x - L.nb0[l];
        if (tid < 64) lh[tid] = 0;
        __syncthreads();
        const int e = bl * 256 + tid;
        if (e < L.E[l]) {
            int b = 0;
            #pragma unroll
            for (int d = 0; d < 3; ++d) {
                const float v = L.u[l][e * 3 + d] * 4.0f;
                const float kf = fminf(fmaxf(floorf(v), 0.f), 3.f);
                b = (b << 2) | (int)kf;
            }
            L.ek0[l][e] = b;
            atomicAdd(&lh[b], 1);
            atomicAdd(&L.deg[l][L.ei[l][L.E[l] + e]], 1.0f);
        }
        __syncthreads();
        if (tid < 64 && lh[tid]) atomicAdd(&L.hist[l][tid], lh[tid]);
    } else {
        // conv1: one wave per edge (64 lanes = 64 out channels)
        const int t = (blockIdx.x - nbTot) * 256 + tid;
        const int e = t >> 6, o = t & 63;
        if (e >= E1) return;
        const int src = L.ei[0][e], dst = L.ei[0][E1 + e];
        float f[3]; int kb = 0;
        #pragma unroll
        for (int d = 0; d < 3; ++d) {
            const float v = L.u[0][e * 3 + d] * 4.0f;
            const float kf = fminf(fmaxf(floorf(v), 0.f), 3.f);
            f[d] = v - kf; kb = kb * 5 + (int)kf;
        }
        float s = 0.f;
        #pragma unroll
        for (int c = 0; c < 8; ++c) {
            const int b0 = (c >> 2) & 1, b1 = (c >> 1) & 1, b2 = c & 1;
            const float wgt = (b0 ? f[0] : 1.f - f[0]) * (b1 ? f[1] : 1.f - f[1]) *
                              (b2 ? f[2] : 1.f - f[2]);
            s += wgt * w1[(size_t)(kb + b0 * 25 + b1 * 5 + b2) * 64 + o];
        }
        atomicAdd(&agg[(size_t)dst * 64 + o], x[src] * s);
    }
}

// Dispatch 3: fill_chunks + scatter (both recompute the 64-bucket prefix scan
// locally from hist) + conv1 node pass.
__global__ __launch_bounds__(256) void fill_scatter_node1(
        Levels L, const float* __restrict__ x, float* __restrict__ agg,
        const float* __restrict__ r1, const float* __restrict__ b1,
        float* __restrict__ h1a, int cbTot, int nbTot) {
    __shared__ int sb[65];
    __shared__ int lh[64], lbase[64];
    const int tid = threadIdx.x;
    const int blk = blockIdx.x;
    if (blk < cbTot) {
        int l = 0;
        while (l < 3 && blk >= L.cb0[l + 1]) ++l;
        if (tid == 0) {
            int cc = 0;
            for (int b = 0; b < 64; ++b) { sb[b] = cc; cc += (L.hist[l][b] + CHUNK - 1) / CHUNK; }
            sb[64] = cc;
        }
        __syncthreads();
        const int c = (blk - L.cb0[l]) * 256 + tid;
        if (c < L.mc[l]) {
            if (c >= sb[64]) { L.ccnt[l][c] = 0; L.ck0[l][c] = 0; }
            else {
                int lo = 0, hi = 64;
                while (hi - lo > 1) { int m = (lo + hi) >> 1; if (sb[m] <= c) lo = m; else hi = m; }
                const int j = c - sb[lo];
                L.ck0[l][c] = lo;
                L.ccnt[l][c] = min(CHUNK, L.hist[l][lo] - j * CHUNK);
            }
        }
    } else if (blk < cbTot + nbTot) {
        const int fb = blk - cbTot;
        int l = 0;
        while (l < 3 && fb >= L.nb0[l + 1]) ++l;
        const int bl = fb - L.nb0[l];
        if (tid == 0) {
            int cc = 0;
            for (int b = 0; b < 64; ++b) { sb[b] = cc; cc += (L.hist[l][b] + CHUNK - 1) / CHUNK; }
        }
        if (tid < 64) lh[tid] = 0;
        __syncthreads();
        const int e = bl * 256 + tid;
        int b = -1, r = 0;
        if (e < L.E[l]) { b = L.ek0[l][e]; r = atomicAdd(&lh[b], 1); }
        __syncthreads();
        if (tid < 64) lbase[tid] = lh[tid] ? atomicAdd(&L.cursor[l][tid], lh[tid]) : 0;
        __syncthreads();
        if (e < L.E[l]) L.perm[l][sb[b] * CHUNK + lbase[b] + r] = e;
    } else {
        // conv1 node pass: out = elu(agg/deg + x*R + b); zero agg after read
        const int nb = blk - cbTot - nbTot;
        const int lane = tid & 63;
        const int grp  = tid >> 6;
        const int n = nb * 4 + grp;
        if (n >= N1) return;
        const float d = fmaxf(L.deg[0][n], 1.f);
        const size_t idx = (size_t)n * 64 + lane;
        float s = agg[idx] / d + b1[lane];
        agg[idx] = 0.f;
        s += x[n] * r1[lane];
        h1a[idx] = eluf(s);
    }
}

// ---------------------------------------------------------------------------
// MFMA bucket-GEMM edge kernel (verified; identical to the 284us round).
// ---------------------------------------------------------------------------
template<int CINMAT, int COUT, bool HAS_ONES>
__global__ __launch_bounds__(256) void bucket_gemm(
        const float* __restrict__ x, const int* __restrict__ ei, const float* __restrict__ u,
        const unsigned short* __restrict__ Wt, const float* __restrict__ Wf,
        const int* __restrict__ perm, const int* __restrict__ ck0, const int* __restrict__ ccnt,
        float* __restrict__ agg, int E) {
    constexpr int ALDA = CINMAT + 8;
    constexpr int KG   = CINMAT / 8;
    constexpr int NT   = COUT / 16;
    constexpr int HALVES = CINMAT / 32;
    constexpr int XS   = CINMAT + (HAS_ONES ? 1 : 0);
    constexpr int IT   = CINMAT / 4;

    __shared__ unsigned short A0s[64 * ALDA], A1s[64 * ALDA];
    __shared__ float gS[64 * 4], sS[64 * 2];
    __shared__ int srcS[64], dstS[64];
    __shared__ float WonesS[HAS_ONES ? 8 * COUT : 4];

    const int chunk = blockIdx.x;
    const int cnt = ccnt[chunk];
    if (cnt == 0) return;
    const int b = ck0[chunk];
    const int kbase = ((b >> 4) & 3) * 25 + ((b >> 2) & 3) * 5 + (b & 3);
    const int cstart = chunk * CHUNK;
    const int tid = threadIdx.x;

    if (tid < CHUNK) {
        const int e = tid;
        const int pe = (e < cnt) ? perm[cstart + e] : -1;
        int sv = -1, dv = 0;
        float g0 = 0, g1 = 0, g2 = 0, g3 = 0, s0 = 0, s1 = 0;
        if (pe >= 0) {
            sv = ei[pe]; dv = ei[E + pe];
            float f[3];
            #pragma unroll
            for (int d2 = 0; d2 < 3; ++d2) {
                const float v = u[pe * 3 + d2] * 4.f;
                const float kf = fminf(fmaxf(floorf(v), 0.f), 3.f);
                f[d2] = v - kf;
            }
            g0 = (1.f - f[0]) * (1.f - f[1]); g1 = (1.f - f[0]) * f[1];
            g2 = f[0] * (1.f - f[1]);         g3 = f[0] * f[1];
            s0 = 1.f - f[2]; s1 = f[2];
        }
        srcS[e] = sv; dstS[e] = dv;
        gS[e * 4 + 0] = g0; gS[e * 4 + 1] = g1; gS[e * 4 + 2] = g2; gS[e * 4 + 3] = g3;
        sS[e * 2 + 0] = s0; sS[e * 2 + 1] = s1;
    }
    if (HAS_ONES) {
        for (int t2 = tid; t2 < 8 * COUT; t2 += 256) {
            const int c = t2 / COUT, o = t2 % COUT;
            const int koff = ((c >> 2) & 1) * 25 + ((c >> 1) & 1) * 5 + (c & 1);
            WonesS[t2] = Wf[((size_t)(kbase + koff) * XS + CINMAT) * COUT + o];
        }
    }
    __syncthreads();

    {   // stage A0/A1 (bf16), 4 threads per edge, IT elems each
        const int e  = tid >> 2;
        const int ib = (tid & 3) * IT;
        const int sv = srcS[e];
        const float sc0 = sS[e * 2], sc1 = sS[e * 2 + 1];
        #pragma unroll
        for (int j = 0; j < IT; j += 2) {
            float x0 = 0.f, x1 = 0.f;
            if (sv >= 0) {
                x0 = x[(size_t)sv * XS + ib + j];
                x1 = x[(size_t)sv * XS + ib + j + 1];
            }
            const unsigned p0 = bfc(x0 * sc0) | ((unsigned)bfc(x1 * sc0) << 16);
            const unsigned p1 = bfc(x0 * sc1) | ((unsigned)bfc(x1 * sc1) << 16);
            *(unsigned*)&A0s[e * ALDA + ib + j] = p0;
            *(unsigned*)&A1s[e * ALDA + ib + j] = p1;
        }
    }
    __syncthreads();

    const int lane = tid & 63;
    const int wid  = tid >> 6;
    const int m0   = wid * 16;
    const int arow = m0 + (lane & 15);
    const int kg   = lane >> 4;
    const int ocol = lane & 15;

    f32x4 acc[4][NT];
    #pragma unroll
    for (int q = 0; q < 4; ++q)
        #pragma unroll
        for (int nt = 0; nt < NT; ++nt) acc[q][nt] = (f32x4){0.f, 0.f, 0.f, 0.f};

    #pragma unroll
    for (int q = 0; q < 4; ++q) {
        #pragma unroll
        for (int b2 = 0; b2 < 2; ++b2) {
            const unsigned short* Ab = b2 ? A1s : A0s;
            const int koff = (q >> 1) * 25 + (q & 1) * 5 + b2;
            #pragma unroll
            for (int hf = 0; hf < HALVES; ++hf) {
                const bfrag a = *(const bfrag*)(Ab + arow * ALDA + hf * 32 + kg * 8);
                const int krow = (kbase + koff) * KG + hf * 4 + kg;
                #pragma unroll
                for (int nt = 0; nt < NT; ++nt) {
                    const bfrag bb = *(const bfrag*)(Wt + ((size_t)krow * COUT + nt * 16 + ocol) * 8);
                    acc[q][nt] = __builtin_amdgcn_mfma_f32_16x16x32_bf16(a, bb, acc[q][nt], 0, 0, 0);
                }
            }
        }
    }

    const int grp = lane >> 4;
    #pragma unroll
    for (int nt = 0; nt < NT; ++nt) {
        const int o = nt * 16 + ocol;
        float wo[8];
        if (HAS_ONES) {
            #pragma unroll
            for (int c = 0; c < 8; ++c) wo[c] = WonesS[c * COUT + o];
        }
        #pragma unroll
        for (int r = 0; r < 4; ++r) {
            const int e = m0 + grp * 4 + r;
            if (e < cnt) {
                const float g0 = gS[e * 4 + 0], g1 = gS[e * 4 + 1];
                const float g2 = gS[e * 4 + 2], g3 = gS[e * 4 + 3];
                float v = g0 * acc[0][nt][r] + g1 * acc[1][nt][r] +
                          g2 * acc[2][nt][r] + g3 * acc[3][nt][r];
                if (HAS_ONES) {
                    const float s0v = sS[e * 2], s1v = sS[e * 2 + 1];
                    v += g0 * (s0v * wo[0] + s1v * wo[1]) + g1 * (s0v * wo[2] + s1v * wo[3]) +
                         g2 * (s0v * wo[4] + s1v * wo[5]) + g3 * (s0v * wo[6] + s1v * wo[7]);
                }
                atomicAdd(&agg[(size_t)dstS[e] * COUT + o], v);
            }
        }
    }
}

// ---------------------------------------------------------------------------
// Fused node kernel. MODE: 0 plain, 1 +segmax pool, 2 +fc1 (64->32), 3 +LSM.
// Zeroes agg after reading (replaces per-conv memset).
// ---------------------------------------------------------------------------
enum { NODE_PLAIN = 0, NODE_SEGMAX = 1, NODE_FC1 = 2, NODE_LSM = 3 };

template<int CIN, int COUT, int MODE>
__global__ void spline_node_f(const float* __restrict__ x, float* __restrict__ agg,
                              const float* __restrict__ deg, const float* __restrict__ R,
                              const float* __restrict__ b, float* __restrict__ out, int N,
                              const int* __restrict__ cl, float* __restrict__ pool,
                              const float* __restrict__ fw, const float* __restrict__ fb2,
                              float* __restrict__ fout) {
    constexpr int NPB = 256 / COUT;
    __shared__ float rowbuf[NPB][COUT];
    const int lane = threadIdx.x % COUT;
    const int grp  = threadIdx.x / COUT;
    const int n = blockIdx.x * NPB + grp;
    if (n >= N) return;
    const float d = fmaxf(deg[n], 1.f);
    const size_t idx = (size_t)n * COUT + lane;
    float s = agg[idx] / d + b[lane];
    agg[idx] = 0.f;
    const float* xs = x + (size_t)n * CIN;
    #pragma unroll 4
    for (int i = 0; i < CIN; ++i) s += xs[i] * R[i * COUT + lane];
    const float val = eluf(s);
    if (MODE == NODE_PLAIN || MODE == NODE_SEGMAX) out[idx] = val;
    if (MODE == NODE_SEGMAX) {
        float* addr = pool + (size_t)cl[n] * 65 + lane;
        if (val >= 0.f) atomicMax((int*)addr, __float_as_int(val));
        else            atomicMin((unsigned int*)addr, __float_as_uint(val));
    }
    if (MODE == NODE_FC1) {          // COUT==64: wave-local fc1 64->32 + elu
        rowbuf[grp][lane] = val;     // 64 lanes = one wave; no barrier needed
        if (lane < 32) {
            float s2 = fb2[lane];
            #pragma unroll 4
            for (int i = 0; i < 64; ++i) s2 += rowbuf[grp][i] * fw[i * 32 + lane];
            fout[(size_t)n * 32 + lane] = eluf(s2);
        }
    }
    if (MODE == NODE_LSM) {          // COUT==32: logits + log_softmax
        float p[NC];
        #pragma unroll
        for (int o = 0; o < NC; ++o) p[o] = val * fw[lane * NC + o];
        #pragma unroll
        for (int m = 16; m >= 1; m >>= 1)
            #pragma unroll
            for (int o = 0; o < NC; ++o) p[o] += __shfl_xor(p[o], m, 32);
        #pragma unroll
        for (int o = 0; o < NC; ++o) p[o] += fb2[o];
        const float mx = fmaxf(fmaxf(p[0], p[1]), fmaxf(p[2], p[3]));
        float se = 0.f;
        #pragma unroll
        for (int o = 0; o < NC; ++o) se += expf(p[o] - mx);
        const float lg = logf(se);
        if (lane < NC) fout[(size_t)n * NC + lane] = p[lane] - mx - lg;
    }
}

__global__ void skip_gather(const float* __restrict__ up, const int* __restrict__ cl,
                            const float* __restrict__ h, const float* __restrict__ skw,
                            const float* __restrict__ skb, float* __restrict__ out, int N) {
    const int lane = threadIdx.x & 31;
    const int grp  = threadIdx.x >> 5;
    const int n = blockIdx.x * 8 + grp;
    if (n >= N) return;
    float s = up[(size_t)cl[n] * 32 + lane] + skb[lane];
    const float* hs = h + (size_t)n * 64;
    #pragma unroll 4
    for (int i = 0; i < 64; ++i) s += hs[i] * skw[i * 32 + lane];
    out[(size_t)n * 32 + lane] = s;
}

// ---------------------------------------------------------------------------
// Host orchestration
// ---------------------------------------------------------------------------
struct HLevel {
    const int* ei; const float* u; int E; int maxchunks;
    int *ek0, *hist, *cursor, *ck0, *ccnt, *perm;
    float* deg;
};

extern "C" void kernel_launch(void* const* d_in, const int* in_sizes, int n_in,
                              void* d_out, int out_size, void* d_ws, size_t ws_size,
                              hipStream_t stream) {
    const float* x    = (const float*)d_in[0];
    const int*   ei1  = (const int*)  d_in[1];
    const float* u1   = (const float*)d_in[2];
    const int*   ei2  = (const int*)  d_in[3];
    const float* u2   = (const float*)d_in[4];
    const int*   ei3  = (const int*)  d_in[5];
    const float* u3   = (const float*)d_in[6];
    const int*   ei4  = (const int*)  d_in[7];
    const float* u4   = (const float*)d_in[8];
    const int*   c1   = (const int*)  d_in[9];
    const int*   c2   = (const int*)  d_in[10];
    const int*   c3   = (const int*)  d_in[11];
    const float *w1  = (const float*)d_in[12], *r1  = (const float*)d_in[13], *b1  = (const float*)d_in[14];
    const float *w12 = (const float*)d_in[15], *r12 = (const float*)d_in[16], *b12 = (const float*)d_in[17];
    const float *w2  = (const float*)d_in[18], *r2  = (const float*)d_in[19], *b2  = (const float*)d_in[20];
    const float *w22 = (const float*)d_in[21], *r22 = (const float*)d_in[22], *b22 = (const float*)d_in[23];
    const float *w3  = (const float*)d_in[24], *r3  = (const float*)d_in[25], *b3  = (const float*)d_in[26];
    const float *w32 = (const float*)d_in[27], *r32 = (const float*)d_in[28], *b32 = (const float*)d_in[29];
    const float *w4  = (const float*)d_in[30], *r4  = (const float*)d_in[31], *b4  = (const float*)d_in[32];
    const float *w42 = (const float*)d_in[33], *r42 = (const float*)d_in[34], *b42 = (const float*)d_in[35];
    const float *w5  = (const float*)d_in[36], *r5  = (const float*)d_in[37], *b5  = (const float*)d_in[38];
    const float *w6  = (const float*)d_in[39], *r6  = (const float*)d_in[40], *b6  = (const float*)d_in[41];
    const float *w7  = (const float*)d_in[42], *r7  = (const float*)d_in[43], *b7  = (const float*)d_in[44];
    const float *fc1w = (const float*)d_in[45], *fc1b = (const float*)d_in[46];
    const float *fc2w = (const float*)d_in[47], *fc2b = (const float*)d_in[48];
    const float *sk1w = (const float*)d_in[49], *sk1b = (const float*)d_in[50];
    const float *sk2w = (const float*)d_in[51], *sk2b = (const float*)d_in[52];
    const float *sk3w = (const float*)d_in[53], *sk3b = (const float*)d_in[54];
    float* out = (float*)d_out;

    char* wsb = (char*)d_ws;
    size_t off = 0;
    auto alloc = [&](size_t bytes) {
        void* p = wsb + off; off = (off + bytes + 255) & ~(size_t)255; return p;
    };
    auto allocF = [&](size_t n) { return (float*)alloc(n * 4); };
    auto allocI = [&](size_t n) { return (int*)alloc(n * 4); };
    auto allocH = [&](size_t n) { return (unsigned short*)alloc(n * 2); };

    float* h1a  = allocF((size_t)N1 * 64);
    float* h1   = allocF((size_t)N1 * 64);
    float* h2in = allocF((size_t)N2 * 65);
    float* h2a  = allocF((size_t)N2 * 64);
    float* h2   = allocF((size_t)N2 * 64);
    float* h3in = allocF((size_t)N3 * 65);
    float* h3a  = allocF((size_t)N3 * 64);
    float* h3   = allocF((size_t)N3 * 64);
    float* h4in = allocF((size_t)N4 * 65);
    float* h4a  = allocF((size_t)N4 * 64);
    float* h4b  = allocF((size_t)N4 * 64);
    float* h4   = allocF((size_t)N4 * 32);
    float* g3in = allocF((size_t)N3 * 32);
    float* g3   = allocF((size_t)N3 * 32);
    float* g2in = allocF((size_t)N2 * 32);
    float* g2   = allocF((size_t)N2 * 32);
    float* g1in = allocF((size_t)N1 * 32);
    float* agg  = allocF((size_t)N1 * 64);

    const size_t SZ64 = (size_t)125 * 8 * 64 * 8;
    const size_t SZ32 = (size_t)125 * 4 * 32 * 8;
    unsigned short* t12 = allocH(SZ64);
    unsigned short* t22 = allocH(SZ64);
    unsigned short* t32 = allocH(SZ64);
    unsigned short* t42 = allocH(SZ64);
    unsigned short* t2  = allocH(SZ64);
    unsigned short* t3  = allocH(SZ64);
    unsigned short* t4  = allocH(SZ64);
    unsigned short* t5  = allocH(SZ32);
    unsigned short* t6  = allocH(SZ32);
    unsigned short* t7  = allocH(SZ32);

    HLevel L[4];
    const int*   eis[4] = {ei1, ei2, ei3, ei4};
    const float* us [4] = {u1, u2, u3, u4};
    const int    Es [4] = {E1, E2, E3, E4};
    const int    Ns [4] = {N1, N2, N3, N4};

    int preN = 0;
    for (int l = 0; l < 4; ++l) preN += 128 + Ns[l];
    int* preblk = allocI(preN);
    {
        int c = 0;
        for (int l = 0; l < 4; ++l) {
            L[l].ei = eis[l]; L[l].u = us[l]; L[l].E = Es[l];
            L[l].maxchunks = (Es[l] + CHUNK - 1) / CHUNK + 64;
            L[l].hist = preblk + c; L[l].cursor = preblk + c + 64;
            L[l].deg = (float*)(preblk + c + 128);
            c += 128 + Ns[l];
            L[l].ek0     = allocI(Es[l]);
            L[l].ck0     = allocI(L[l].maxchunks);
            L[l].ccnt    = allocI(L[l].maxchunks);
            L[l].perm    = allocI((size_t)L[l].maxchunks * CHUNK);
        }
    }

    // ---- dispatch 1: init_misc ----
    InitArgs IA;
    {
        const float* srcs[10] = {w12, w22, w32, w42, w2, w3, w4, w5, w6, w7};
        unsigned short* dsts[10] = {t12, t22, t32, t42, t2, t3, t4, t5, t6, t7};
        const int cms[10] = {64,64,64,64,64,64,64,32,32,32};
        const int xss[10] = {64,64,64,64,65,65,65,32,32,32};
        const int cos[10] = {64,64,64,64,64,64,64,32,32,32};
        long cum = 0;
        for (int k = 0; k < 10; ++k) {
            IA.wsrc[k] = srcs[k]; IA.wdst[k] = dsts[k];
            IA.cinmat[k] = cms[k]; IA.xs_[k] = xss[k]; IA.cout[k] = cos[k];
            cum += (long)125 * (cms[k] / 8) * cos[k];     // 8-groups
            IA.welems[k] = cum;
        }
        IA.wtot = cum;
        IA.pools[0] = h2in; IA.pools[1] = h3in; IA.pools[2] = h4in;
        IA.pM[0] = N2 * 65; IA.pM[1] = N2 * 65 + N3 * 65; IA.pM[2] = N2 * 65 + N3 * 65 + N4 * 65;
        IA.agg = agg; IA.aggN4 = N1 * 64 / 4;
        IA.preblk = preblk; IA.preN = preN;
        const int bA = (int)((IA.wtot + 255) / 256);
        const int bB = (IA.pM[2] + 255) / 256;
        const int bC = (IA.aggN4 + 255) / 256;
        const int bD = (preN + 255) / 256;
        IA.bB = bA; IA.bC = bA + bB; IA.bD = bA + bB + bC;
        init_misc<<<bA + bB + bC + bD, 256, 0, stream>>>(IA);
    }

    // ---- dispatches 2-3: preprocessing + conv1 ----
    Levels DL;
    int nbTot = 0, cbTot = 0;
    {
        for (int l = 0; l < 4; ++l) {
            DL.u[l] = L[l].u; DL.ei[l] = L[l].ei; DL.E[l] = L[l].E;
            DL.nb0[l] = nbTot; nbTot += (L[l].E + 255) / 256;
            DL.cb0[l] = cbTot; cbTot += (L[l].maxchunks + 255) / 256;
            DL.mc[l] = L[l].maxchunks;
            DL.ek0[l] = L[l].ek0; DL.hist[l] = L[l].hist; DL.cursor[l] = L[l].cursor;
            DL.deg[l] = L[l].deg;
            DL.ck0[l] = L[l].ck0; DL.ccnt[l] = L[l].ccnt; DL.perm[l] = L[l].perm;
        }
        DL.nb0[4] = nbTot; DL.cb0[4] = cbTot;
        const int conv1B = (E1 * 64) / 256;
        prep_conv1<<<nbTot + conv1B, 256, 0, stream>>>(DL, x, w1, agg, nbTot);
        const int n1B = (N1 + 3) / 4;
        fill_scatter_node1<<<cbTot + nbTot + n1B, 256, 0, stream>>>(
            DL, x, agg, r1, b1, h1a, cbTot, nbTot);
    }

    // ---- Level 1 ----
    bucket_gemm<64, 64, false><<<L[0].maxchunks, 256, 0, stream>>>(
        h1a, L[0].ei, L[0].u, t12, nullptr, L[0].perm, L[0].ck0, L[0].ccnt, agg, L[0].E);
    spline_node_f<64, 64, NODE_SEGMAX><<<(N1 + 3) / 4, 256, 0, stream>>>(
        h1a, agg, L[0].deg, r12, b12, h1, N1, c1, h2in, nullptr, nullptr, nullptr);

    // ---- Level 2 ----
    bucket_gemm<64, 64, true><<<L[1].maxchunks, 256, 0, stream>>>(
        h2in, L[1].ei, L[1].u, t2, w2, L[1].perm, L[1].ck0, L[1].ccnt, agg, L[1].E);
    spline_node_f<65, 64, NODE_PLAIN><<<(N2 + 3) / 4, 256, 0, stream>>>(
        h2in, agg, L[1].deg, r2, b2, h2a, N2, nullptr, nullptr, nullptr, nullptr, nullptr);
    bucket_gemm<64, 64, false><<<L[1].maxchunks, 256, 0, stream>>>(
        h2a, L[1].ei, L[1].u, t22, nullptr, L[1].perm, L[1].ck0, L[1].ccnt, agg, L[1].E);
    spline_node_f<64, 64, NODE_SEGMAX><<<(N2 + 3) / 4, 256, 0, stream>>>(
        h2a, agg, L[1].deg, r22, b22, h2, N2, c2, h3in, nullptr, nullptr, nullptr);

    // ---- Level 3 ----
    bucket_gemm<64, 64, true><<<L[2].maxchunks, 256, 0, stream>>>(
        h3in, L[2].ei, L[2].u, t3, w3, L[2].perm, L[2].ck0, L[2].ccnt, agg, L[2].E);
    spline_node_f<65, 64, NODE_PLAIN><<<(N3 + 3) / 4, 256, 0, stream>>>(
        h3in, agg, L[2].deg, r3, b3, h3a, N3, nullptr, nullptr, nullptr, nullptr, nullptr);
    bucket_gemm<64, 64, false><<<L[2].maxchunks, 256, 0, stream>>>(
        h3a, L[2].ei, L[2].u, t32, nullptr, L[2].perm, L[2].ck0, L[2].ccnt, agg, L[2].E);
    spline_node_f<64, 64, NODE_SEGMAX><<<(N3 + 3) / 4, 256, 0, stream>>>(
        h3a, agg, L[2].deg, r32, b32, h3, N3, c3, h4in, nullptr, nullptr, nullptr);

    // ---- Level 4 ----
    bucket_gemm<64, 64, true><<<L[3].maxchunks, 256, 0, stream>>>(
        h4in, L[3].ei, L[3].u, t4, w4, L[3].perm, L[3].ck0, L[3].ccnt, agg, L[3].E);
    spline_node_f<65, 64, NODE_PLAIN><<<(N4 + 3) / 4, 256, 0, stream>>>(
        h4in, agg, L[3].deg, r4, b4, h4a, N4, nullptr, nullptr, nullptr, nullptr, nullptr);
    bucket_gemm<64, 64, false><<<L[3].maxchunks, 256, 0, stream>>>(
        h4a, L[3].ei, L[3].u, t42, nullptr, L[3].perm, L[3].ck0, L[3].ccnt, agg, L[3].E);
    spline_node_f<64, 64, NODE_PLAIN><<<(N4 + 3) / 4, 256, 0, stream>>>(
        h4a, agg, L[3].deg, r42, b42, h4b, N4, nullptr, nullptr, nullptr, nullptr, nullptr);
    bucket_gemm<64, 64, false><<<L[3].maxchunks, 256, 0, stream>>>(
        h4b, L[3].ei, L[3].u, t42, nullptr, L[3].perm, L[3].ck0, L[3].ccnt, agg, L[3].E);
    // conv42 node (2nd application) + fused fc1 -> h4 [N4,32]
    spline_node_f<64, 64, NODE_FC1><<<(N4 + 3) / 4, 256, 0, stream>>>(
        h4b, agg, L[3].deg, r42, b42, nullptr, N4, nullptr, nullptr, fc1w, fc1b, h4);

    // ---- Decoder ----
    skip_gather<<<(N3 + 7) / 8, 256, 0, stream>>>(h4, c3, h3, sk3w, sk3b, g3in, N3);
    bucket_gemm<32, 32, false><<<L[2].maxchunks, 256, 0, stream>>>(
        g3in, L[2].ei, L[2].u, t5, nullptr, L[2].perm, L[2].ck0, L[2].ccnt, agg, L[2].E);
    spline_node_f<32, 32, NODE_PLAIN><<<(N3 + 7) / 8, 256, 0, stream>>>(
        g3in, agg, L[2].deg, r5, b5, g3, N3, nullptr, nullptr, nullptr, nullptr, nullptr);

    skip_gather<<<(N2 + 7) / 8, 256, 0, stream>>>(g3, c2, h2, sk2w, sk2b, g2in, N2);
    bucket_gemm<32, 32, false><<<L[1].maxchunks, 256, 0, stream>>>(
        g2in, L[1].ei, L[1].u, t6, nullptr, L[1].perm, L[1].ck0, L[1].ccnt, agg, L[1].E);
    spline_node_f<32, 32, NODE_PLAIN><<<(N2 + 7) / 8, 256, 0, stream>>>(
        g2in, agg, L[1].deg, r6, b6, g2, N2, nullptr, nullptr, nullptr, nullptr, nullptr);

    skip_gather<<<(N1 + 7) / 8, 256, 0, stream>>>(g2, c1, h1, sk1w, sk1b, g1in, N1);
    bucket_gemm<32, 32, false><<<L[0].maxchunks, 256, 0, stream>>>(
        g1in, L[0].ei, L[0].u, t7, nullptr, L[0].perm, L[0].ck0, L[0].ccnt, agg, L[0].E);
    spline_node_f<32, 32, NODE_LSM><<<(N1 + 7) / 8, 256, 0, stream>>>(
        g1in, agg, L[0].deg, r7, b7, nullptr, N1, nullptr, nullptr, fc2w, fc2b, out);
}